// Round 2
// baseline (795.079 us; speedup 1.0000x reference)
//
#include <hip/hip_runtime.h>

// RecNN: u = relu(contents @ W_u^T + b_u); 10 levels of
// emb = relu([emb_L, emb_R, u_j] @ W_h^T + b_h).
//
// Key decomposition: W_h @ [hL; hR; u] = W_L@hL + W_R@hR + W_hu@u.
// The u-term has no cross-level dependency -> hoisted into one big GEMM
// v = u[internal] @ W_hu^T (34.3 GFLOP, fully parallel). Level GEMMs then
// run with K=1024 (children only) and add v in the epilogue, cutting the
// serial chain's FLOPs and latency floor by 1/3.
//
// All GEMMs: m97 structure (128x128 tile, BK=32, 4 waves, glds width=16,
// 16x16x32 bf16 MFMA, fp32 accum). Activations bf16 in workspace.

typedef unsigned short u16;
typedef __attribute__((ext_vector_type(8))) short bf16x8;
typedef __attribute__((ext_vector_type(4))) float f32x4;

#define TILE 128
#define BK 32

__device__ __forceinline__ u16 f2b(float f) {
  union { float f; unsigned u; } c; c.f = f;
  unsigned u = c.u;
  return (u16)((u + 0x7fffu + ((u >> 16) & 1u)) >> 16);  // RNE
}

__device__ __forceinline__ float b2f(unsigned hi16) {
  union { float f; unsigned u; } c; c.u = hi16 << 16; return c.f;
}

__device__ __forceinline__ void glds16(const void* g, void* l) {
  __builtin_amdgcn_global_load_lds(
      (__attribute__((address_space(1))) void*)g,
      (__attribute__((address_space(3))) void*)l, 16, 0, 0);
}

// MODE 0: plain bf16 A [M][K], epilogue bias+relu        (GEMM1)
// MODE 2: plain bf16 A [M][K], raw store (no bias/relu)  (v-GEMM)
// MODE 1: A gathered [emb[c.x] | emb[c.y]] (K=1024), epilogue v+bias+relu
template <int MODE>
__global__ __launch_bounds__(256)
void gemm_bt(const u16* __restrict__ A,
             const u16* __restrict__ embPrev,
             const int2* __restrict__ idx,
             const u16* __restrict__ vLvl,   // [M][512] bf16
             const u16* __restrict__ W,      // [512][ldb] bf16 (B^T layout)
             int ldb,
             const float* __restrict__ bias,
             u16* __restrict__ out,          // [M][512] bf16
             int M, int K) {
  __shared__ __align__(16) u16 lA[TILE * BK];
  __shared__ __align__(16) u16 lB[TILE * BK];

  const int tid  = threadIdx.x;
  const int lane = tid & 63;
  const int wv   = tid >> 6;
  const int wrow = wv >> 1, wcol = wv & 1;
  const int mBase = blockIdx.y * TILE;
  const int n0    = blockIdx.x * TILE;

  const int rowA0 = tid >> 2;       // 0..63  (round 0)
  const int rowA1 = rowA0 + 64;     // 64..127 (round 1)
  const int q     = tid & 3;
  const int colq  = q * 8;

  const u16 *a0 = nullptr, *a1 = nullptr;
  const u16 *aL0 = nullptr, *aR0 = nullptr;
  const u16 *aL1 = nullptr, *aR1 = nullptr;
  {
    int m0 = min(mBase + rowA0, M - 1);
    int m1 = min(mBase + rowA1, M - 1);
    if (MODE == 0 || MODE == 2) {
      a0 = A + (size_t)m0 * K;
      a1 = A + (size_t)m1 * K;
    } else {
      int2 c0 = idx[m0], c1 = idx[m1];
      aL0 = embPrev + (size_t)c0.x * 512;
      aR0 = embPrev + (size_t)c0.y * 512;
      aL1 = embPrev + (size_t)c1.x * 512;
      aR1 = embPrev + (size_t)c1.y * 512;
    }
  }
  const u16* bp0 = W + (size_t)(n0 + rowA0) * ldb;
  const u16* bp1 = W + (size_t)(n0 + rowA1) * ldb;

  f32x4 acc[4][4] = {};

  const int fm = lane & 15;
  const int kk = (lane >> 4) * 8;

  for (int k0 = 0; k0 < K; k0 += BK) {
    __syncthreads();
    if (MODE == 0 || MODE == 2) {
      int col = k0 + colq;
      glds16(a0 + col, &lA[(tid) * 8]);
      glds16(a1 + col, &lA[(tid + 256) * 8]);
    } else {
      int seg = k0 >> 9;                  // 0: left child, 1: right child
      int col = (k0 & 511) + colq;
      const u16* g0 = (seg == 0 ? aL0 : aR0) + col;
      const u16* g1 = (seg == 0 ? aL1 : aR1) + col;
      glds16(g0, &lA[(tid) * 8]);
      glds16(g1, &lA[(tid + 256) * 8]);
    }
    {
      int col = k0 + colq;
      glds16(bp0 + col, &lB[(tid) * 8]);
      glds16(bp1 + col, &lB[(tid + 256) * 8]);
    }
    __syncthreads();

    bf16x8 av[4], bv[4];
#pragma unroll
    for (int i = 0; i < 4; i++) {
      av[i] = *(const bf16x8*)&lA[(wrow * 64 + i * 16 + fm) * BK + kk];
      bv[i] = *(const bf16x8*)&lB[(wcol * 64 + i * 16 + fm) * BK + kk];
    }
#pragma unroll
    for (int i = 0; i < 4; i++)
#pragma unroll
      for (int j = 0; j < 4; j++)
        acc[i][j] = __builtin_amdgcn_mfma_f32_16x16x32_bf16(av[i], bv[j], acc[i][j], 0, 0, 0);
  }

  // Epilogue: C/D layout col=lane&15, row=(lane>>4)*4+reg (m89-verified).
  const int r0 = (lane >> 4) * 4;
#pragma unroll
  for (int i = 0; i < 4; i++) {
    int mI = mBase + wrow * 64 + i * 16 + r0;
#pragma unroll
    for (int j = 0; j < 4; j++) {
      int col = n0 + wcol * 64 + j * 16 + fm;
      float bvv = (MODE == 2) ? 0.f : bias[col];
#pragma unroll
      for (int r = 0; r < 4; r++) {
        int m = mI + r;
        if (m < M) {
          float v = acc[i][j][r] + bvv;
          if (MODE == 1) v += b2f(vLvl[(size_t)m * 512 + col]);
          if (MODE != 2) v = v > 0.f ? v : 0.f;
          out[(size_t)m * 512 + col] = f2b(v);
        }
      }
    }
  }
}

__global__ void cvt_f32_to_bf16(const float* __restrict__ src, u16* __restrict__ dst, int n8) {
  int i = blockIdx.x * blockDim.x + threadIdx.x;
  if (i >= n8) return;
  const float4* s = (const float4*)src;
  float4 a = s[2 * i], b = s[2 * i + 1];
  union { u16 u[8]; bf16x8 v; } o;
  o.u[0] = f2b(a.x); o.u[1] = f2b(a.y); o.u[2] = f2b(a.z); o.u[3] = f2b(a.w);
  o.u[4] = f2b(b.x); o.u[5] = f2b(b.y); o.u[6] = f2b(b.z); o.u[7] = f2b(b.w);
  *(bf16x8*)(dst + (size_t)i * 8) = o.v;
}

// Extract W_h columns [1024,1536) -> packed [512][512] bf16 (W_hu part)
__global__ void cvt_slice_bf16(const float* __restrict__ Wh, u16* __restrict__ dst, int n8) {
  int i = blockIdx.x * blockDim.x + threadIdx.x;
  if (i >= n8) return;                 // n8 = 512*512/8
  int row = i >> 6;                    // 512/8 = 64 chunks per row
  int c8  = (i & 63) * 8;
  const float4* s = (const float4*)(Wh + (size_t)row * 1536 + 1024 + c8);
  float4 a = s[0], b = s[1];
  union { u16 u[8]; bf16x8 v; } o;
  o.u[0] = f2b(a.x); o.u[1] = f2b(a.y); o.u[2] = f2b(a.z); o.u[3] = f2b(a.w);
  o.u[4] = f2b(b.x); o.u[5] = f2b(b.y); o.u[6] = f2b(b.z); o.u[7] = f2b(b.w);
  *(bf16x8*)(dst + (size_t)row * 512 + c8) = o.v;
}

__global__ void cvt_bf16_to_f32(const u16* __restrict__ src, float* __restrict__ dst, int n4) {
  int i = blockIdx.x * blockDim.x + threadIdx.x;
  if (i >= n4) return;
  uint2 p = ((const uint2*)src)[i];
  float4 o;
  o.x = b2f(p.x & 0xffffu); o.y = b2f(p.x >> 16);
  o.z = b2f(p.y & 0xffffu); o.w = b2f(p.y >> 16);
  ((float4*)dst)[i] = o;
}

extern "C" void kernel_launch(void* const* d_in, const int* in_sizes, int n_in,
                              void* d_out, int out_size, void* d_ws, size_t ws_size,
                              hipStream_t stream) {
  const float* contents = (const float*)d_in[0];
  const int2*  children = (const int2*)d_in[1];
  const float* W_u = (const float*)d_in[2];
  const float* b_u = (const float*)d_in[3];
  const float* W_h = (const float*)d_in[4];
  const float* b_h = (const float*)d_in[5];
  float* out = (float*)d_out;

  const int B = 64, D = 11, F = 256, H = 512;
  const int N = B * ((1 << D) - 1);            // 131008 nodes
  const int NI = B * ((1 << (D - 1)) - 1);     // 65472 internal nodes
  const int NL = B << (D - 1);                 // 65536 leaves

  // Workspace (u16 elements):
  //   u_bf  [N*512]          @ 0                (134.2 MB)
  //   C     [33,554,432]     @ 67,076,096       (67.1 MB: contents_bf16, then v)
  //   Wub   [512*256], Whb [512*1536], Wvb [512*512]
  // emb ping-pong aliases u_bf's internal rows (dead after v-GEMM).
  u16* ws16 = (u16*)d_ws;
  u16* u_bf = ws16;
  u16* C    = ws16 + (size_t)N * H;            // 67,076,096
  u16* Wub  = C + 33554432;
  u16* Whb  = Wub + 512 * 256;
  u16* Wvb  = Whb + 512 * 1536;

  u16* cont_bf = C;                            // phase 1
  u16* v_bf    = C;                            // phase 2 (contents dead)
  u16* embA = u_bf;                            // aliases dead u-internal rows
  u16* embB = u_bf + (size_t)16384 * 512;      // 16.7M elems in, still internal

  // --- weight + input conversions ---
  {
    int n8 = N * F / 8;
    cvt_f32_to_bf16<<<(n8 + 255) / 256, 256, 0, stream>>>(contents, cont_bf, n8);
    n8 = H * F / 8;
    cvt_f32_to_bf16<<<(n8 + 255) / 256, 256, 0, stream>>>(W_u, Wub, n8);
    n8 = H * 3 * H / 8;
    cvt_f32_to_bf16<<<(n8 + 255) / 256, 256, 0, stream>>>(W_h, Whb, n8);
    n8 = H * H / 8;
    cvt_slice_bf16<<<(n8 + 255) / 256, 256, 0, stream>>>(W_h, Wvb, n8);
  }

  // --- GEMM1: u = relu(contents_bf @ W_u^T + b_u) ---
  {
    dim3 g(512 / TILE, (N + TILE - 1) / TILE);
    gemm_bt<0><<<g, 256, 0, stream>>>(cont_bf, nullptr, nullptr, nullptr,
                                      Wub, F, b_u, u_bf, N, F);
  }

  // --- v-GEMM: v = u[0:NI] @ W_hu^T (raw, no bias/relu) ---
  {
    dim3 g(512 / TILE, (NI + TILE - 1) / TILE);
    gemm_bt<2><<<g, 256, 0, stream>>>(u_bf, nullptr, nullptr, nullptr,
                                      Wvb, H, nullptr, v_bf, NI, H);
  }

  // --- tree levels j = D-2 .. 0 (K=1024: children only; v in epilogue) ---
  const u16* embPrev = u_bf + (size_t)NI * H;  // leaves = u[NI : NI+NL]
  u16* dst = embA;
  for (int j = D - 2; j >= 0; --j) {
    int M = B << j;
    int o = B * ((1 << j) - 1);
    dim3 g(512 / TILE, (M + TILE - 1) / TILE);
    gemm_bt<1><<<g, 256, 0, stream>>>(nullptr, embPrev, children + o,
                                      v_bf + (size_t)o * H,
                                      Whb, 3 * H, b_h, dst, M, 2 * H);
    embPrev = dst;
    dst = (dst == embA) ? embB : embA;
  }

  // --- level-0 emb (64 x 512) -> fp32 output ---
  {
    int n4 = B * H / 4;
    cvt_bf16_to_f32<<<(n4 + 255) / 256, 256, 0, stream>>>(embPrev, out, n4);
  }
}

// Round 3
// 709.372 us; speedup vs baseline: 1.1208x; 1.1208x over previous
//
#include <hip/hip_runtime.h>
#include <hip/hip_bf16.h>

// RecNN: u = relu(contents @ W_u^T + b_u); v = u[internal] @ W_hu^T (hoisted,
// parallel); 10 levels emb = relu([emb_L|emb_R] @ W_LR^T + v + b_h).
//
// Round-3 structure: TILE_N = 512 (full output width, grid.x == 1) so every
// A row is fetched exactly ONCE (round 2's grid.x=4 re-read was the dominant
// waste: v-GEMM fetched 150 MB for a 67 MB A). 256 threads, TILE_M=64,
// 4 waves each 64x128 (acc[4][8]), BK=32, glds width=16 staging, 16x16x32
// bf16 MFMA. GEMM1 converts fp32 contents in-staging (packed cvt) -- no
// separate convert pass.

typedef unsigned short u16;
typedef __attribute__((ext_vector_type(8))) short bf16x8;
typedef __attribute__((ext_vector_type(4))) float f32x4;

#define BK 32

__device__ __forceinline__ u16 f2b(float f) {
  union { float f; unsigned u; } c; c.f = f;
  unsigned u = c.u;
  return (u16)((u + 0x7fffu + ((u >> 16) & 1u)) >> 16);  // RNE
}

__device__ __forceinline__ float b2f(unsigned hi16) {
  union { float f; unsigned u; } c; c.u = hi16 << 16; return c.f;
}

__device__ __forceinline__ void glds16(const void* g, void* l) {
  __builtin_amdgcn_global_load_lds(
      (__attribute__((address_space(1))) void*)g,
      (__attribute__((address_space(3))) void*)l, 16, 0, 0);
}

// MODE 0: A fp32 [M][K], convert in staging; epilogue bias+relu   (GEMM1)
// MODE 2: A bf16 [M][K] linear; raw store                         (v-GEMM)
// MODE 1: A gathered [emb[c.x] | emb[c.y]] (K=1024); +v+bias+relu (levels)
template <int MODE>
__global__ __launch_bounds__(256, 2)
void gemm_n512(const float* __restrict__ Af32,
               const u16* __restrict__ Abf,
               const u16* __restrict__ embPrev,
               const int2* __restrict__ idx,
               const u16* __restrict__ vLvl,   // [M][512] bf16
               const u16* __restrict__ W,      // [512][ldb] bf16 (B^T)
               int ldb,
               const float* __restrict__ bias,
               u16* __restrict__ out,          // [M][512] bf16
               int K) {
  __shared__ __align__(16) u16 lA[64 * BK];    // 4 KB
  __shared__ __align__(16) u16 lB[512 * BK];   // 32 KB

  const int tid  = threadIdx.x;
  const int lane = tid & 63;
  const int wv   = tid >> 6;          // wave = 128-wide N slice
  const int mBase = blockIdx.x * 64;  // M always a multiple of 64 here

  const int row  = tid >> 2;          // 0..63
  const int q    = tid & 3;
  const int colq = q * 8;

  const float* af = nullptr;
  const u16 *ab = nullptr, *aL = nullptr, *aR = nullptr;
  if (MODE == 0) {
    af = Af32 + (size_t)(mBase + row) * K;
  } else if (MODE == 2) {
    ab = Abf + (size_t)(mBase + row) * K;
  } else {
    int2 c = idx[mBase + row];
    aL = embPrev + (size_t)c.x * 512;
    aR = embPrev + (size_t)c.y * 512;
  }
  const u16* bp = W + (size_t)row * ldb + colq;

  f32x4 acc[4][8] = {};

  const int fm = lane & 15;
  const int kk = (lane >> 4) * 8;

  for (int k0 = 0; k0 < K; k0 += BK) {
    __syncthreads();
    // --- stage A (64 x 32) ---
    if (MODE == 0) {
      const float4* s = (const float4*)(af + k0 + colq);
      float4 x = s[0], y = s[1];
      union { __hip_bfloat162 h[4]; bf16x8 v; } o;
      o.h[0] = __float22bfloat162_rn({x.x, x.y});
      o.h[1] = __float22bfloat162_rn({x.z, x.w});
      o.h[2] = __float22bfloat162_rn({y.x, y.y});
      o.h[3] = __float22bfloat162_rn({y.z, y.w});
      *(bf16x8*)&lA[tid * 8] = o.v;
    } else if (MODE == 2) {
      glds16(ab + k0 + colq, &lA[tid * 8]);
    } else {
      const u16* g = ((k0 & 512) ? aR : aL) + (k0 & 511) + colq;
      glds16(g, &lA[tid * 8]);
    }
    // --- stage B (512 x 32) ---
#pragma unroll
    for (int r = 0; r < 8; r++)
      glds16(bp + (size_t)(r * 64) * ldb + k0, &lB[(r * 256 + tid) * 8]);
    __syncthreads();

    bf16x8 av[4], bv[8];
#pragma unroll
    for (int i = 0; i < 4; i++)
      av[i] = *(const bf16x8*)&lA[(i * 16 + fm) * BK + kk];
#pragma unroll
    for (int j = 0; j < 8; j++)
      bv[j] = *(const bf16x8*)&lB[(wv * 128 + j * 16 + fm) * BK + kk];
#pragma unroll
    for (int i = 0; i < 4; i++)
#pragma unroll
      for (int j = 0; j < 8; j++)
        acc[i][j] = __builtin_amdgcn_mfma_f32_16x16x32_bf16(av[i], bv[j], acc[i][j], 0, 0, 0);
  }

  // Epilogue: C/D layout col=lane&15, row=(lane>>4)*4+reg (m89-verified).
  const int r0 = (lane >> 4) * 4;
#pragma unroll
  for (int i = 0; i < 4; i++) {
#pragma unroll
    for (int j = 0; j < 8; j++) {
      int col = wv * 128 + j * 16 + fm;
      float bb = (MODE == 2) ? 0.f : bias[col];
#pragma unroll
      for (int r = 0; r < 4; r++) {
        int m = mBase + i * 16 + r0 + r;
        float v = acc[i][j][r] + bb;
        if (MODE == 1) v += b2f(vLvl[(size_t)m * 512 + col]);
        if (MODE != 2) v = v > 0.f ? v : 0.f;
        out[(size_t)m * 512 + col] = f2b(v);
      }
    }
  }
}

__global__ void cvt_f32_to_bf16(const float* __restrict__ src, u16* __restrict__ dst, int n8) {
  int i = blockIdx.x * blockDim.x + threadIdx.x;
  if (i >= n8) return;
  const float4* s = (const float4*)src;
  float4 a = s[2 * i], b = s[2 * i + 1];
  union { u16 u[8]; bf16x8 v; } o;
  o.u[0] = f2b(a.x); o.u[1] = f2b(a.y); o.u[2] = f2b(a.z); o.u[3] = f2b(a.w);
  o.u[4] = f2b(b.x); o.u[5] = f2b(b.y); o.u[6] = f2b(b.z); o.u[7] = f2b(b.w);
  *(bf16x8*)(dst + (size_t)i * 8) = o.v;
}

// Extract W_h columns [1024,1536) -> packed [512][512] bf16 (W_hu part)
__global__ void cvt_slice_bf16(const float* __restrict__ Wh, u16* __restrict__ dst, int n8) {
  int i = blockIdx.x * blockDim.x + threadIdx.x;
  if (i >= n8) return;                 // n8 = 512*512/8
  int row = i >> 6;
  int c8  = (i & 63) * 8;
  const float4* s = (const float4*)(Wh + (size_t)row * 1536 + 1024 + c8);
  float4 a = s[0], b = s[1];
  union { u16 u[8]; bf16x8 v; } o;
  o.u[0] = f2b(a.x); o.u[1] = f2b(a.y); o.u[2] = f2b(a.z); o.u[3] = f2b(a.w);
  o.u[4] = f2b(b.x); o.u[5] = f2b(b.y); o.u[6] = f2b(b.z); o.u[7] = f2b(b.w);
  *(bf16x8*)(dst + (size_t)row * 512 + c8) = o.v;
}

__global__ void cvt_bf16_to_f32(const u16* __restrict__ src, float* __restrict__ dst, int n4) {
  int i = blockIdx.x * blockDim.x + threadIdx.x;
  if (i >= n4) return;
  uint2 p = ((const uint2*)src)[i];
  float4 o;
  o.x = b2f(p.x & 0xffffu); o.y = b2f(p.x >> 16);
  o.z = b2f(p.y & 0xffffu); o.w = b2f(p.y >> 16);
  ((float4*)dst)[i] = o;
}

extern "C" void kernel_launch(void* const* d_in, const int* in_sizes, int n_in,
                              void* d_out, int out_size, void* d_ws, size_t ws_size,
                              hipStream_t stream) {
  const float* contents = (const float*)d_in[0];
  const int2*  children = (const int2*)d_in[1];
  const float* W_u = (const float*)d_in[2];
  const float* b_u = (const float*)d_in[3];
  const float* W_h = (const float*)d_in[4];
  const float* b_h = (const float*)d_in[5];
  float* out = (float*)d_out;

  const int B = 64, D = 11, F = 256, H = 512;
  const int N = B * ((1 << D) - 1);            // 131008 nodes
  const int NI = B * ((1 << (D - 1)) - 1);     // 65472 internal nodes

  // Workspace (u16 elems): u_bf [N*512] | v_bf [NI*512] | Wub | Whb | Wvb.
  // emb ping-pong aliases u's internal rows (dead after the v-GEMM):
  //   embA = u_bf[0 .. 16.8M)   (level-9 dst, 32768 rows)
  //   embB = u_bf[16.8M .. 25.2M) (<=16384 rows)
  u16* ws16 = (u16*)d_ws;
  u16* u_bf = ws16;
  u16* v_bf = ws16 + (size_t)N * H;
  u16* Wub  = v_bf + (size_t)NI * H;
  u16* Whb  = Wub + 512 * 256;
  u16* Wvb  = Whb + 512 * 1536;
  u16* embA = u_bf;
  u16* embB = u_bf + (size_t)32768 * 512;

  // --- weight conversions (tiny) ---
  {
    int n8 = H * F / 8;
    cvt_f32_to_bf16<<<(n8 + 255) / 256, 256, 0, stream>>>(W_u, Wub, n8);
    n8 = H * 3 * H / 8;
    cvt_f32_to_bf16<<<(n8 + 255) / 256, 256, 0, stream>>>(W_h, Whb, n8);
    n8 = H * H / 8;
    cvt_slice_bf16<<<(n8 + 255) / 256, 256, 0, stream>>>(W_h, Wvb, n8);
  }

  // --- GEMM1: u = relu(contents @ W_u^T + b_u), fp32 A in-staging cvt ---
  gemm_n512<0><<<N / 64, 256, 0, stream>>>(contents, nullptr, nullptr, nullptr,
                                           nullptr, Wub, F, b_u, u_bf, F);

  // --- v-GEMM: v = u[0:NI] @ W_hu^T (raw) ---
  gemm_n512<2><<<NI / 64, 256, 0, stream>>>(nullptr, u_bf, nullptr, nullptr,
                                            nullptr, Wvb, H, nullptr, v_bf, H);

  // --- tree levels j = D-2 .. 0 (K=1024 children; v in epilogue) ---
  const u16* embPrev = u_bf + (size_t)NI * H;  // leaves = u[NI:]
  u16* dst = embA;
  for (int j = D - 2; j >= 0; --j) {
    int M = B << j;
    int o = B * ((1 << j) - 1);
    gemm_n512<1><<<M / 64, 256, 0, stream>>>(nullptr, nullptr, embPrev,
                                             children + o, v_bf + (size_t)o * H,
                                             Whb, 3 * H, b_h, dst, 2 * H);
    embPrev = dst;
    dst = (dst == embA) ? embB : embA;
  }

  // --- level-0 emb (64 x 512) -> fp32 output ---
  {
    int n4 = B * H / 4;
    cvt_bf16_to_f32<<<(n4 + 255) / 256, 256, 0, stream>>>(embPrev, out, n4);
  }
}

// Round 4
// 693.955 us; speedup vs baseline: 1.1457x; 1.0222x over previous
//
#include <hip/hip_runtime.h>
#include <hip/hip_bf16.h>

// RecNN: u = relu(contents @ W_u^T + b_u); v = u[internal] @ W_hu^T (hoisted);
// 10 levels emb = relu([emb_L|emb_R] @ W_LR^T + v + b_h).
//
// Round-4 structure: 128x128 block tile (4 waves, 64x64 each, acc[4][4] =
// 64 AGPR -> 3 blocks/CU), BK=32, EXPLICIT double-buffered LDS with one
// barrier per k-step (next tile's glds issued right after the barrier, so
// it overlaps the whole MFMA stage), and XCD swizzle so the 4 n-blocks of
// one m-block run on the same XCD (A re-reads served from that XCD's L2).
// v-GEMM reads W_hu in place from W_h via ldb=1536 (no slice copy).

typedef unsigned short u16;
typedef __attribute__((ext_vector_type(8))) short bf16x8;
typedef __attribute__((ext_vector_type(4))) float f32x4;

#define BK 32

__device__ __forceinline__ u16 f2b(float f) {
  union { float f; unsigned u; } c; c.f = f;
  unsigned u = c.u;
  return (u16)((u + 0x7fffu + ((u >> 16) & 1u)) >> 16);  // RNE
}

__device__ __forceinline__ float b2f(unsigned hi16) {
  union { float f; unsigned u; } c; c.u = hi16 << 16; return c.f;
}

__device__ __forceinline__ void glds16(const void* g, void* l) {
  __builtin_amdgcn_global_load_lds(
      (__attribute__((address_space(1))) void*)g,
      (__attribute__((address_space(3))) void*)l, 16, 0, 0);
}

// MODE 0: A fp32 [M][K] (convert in staging), epilogue bias+relu   (GEMM1)
// MODE 2: A bf16 [M][K], raw store                                 (v-GEMM)
// MODE 1: A gathered [emb[c.x] | emb[c.y]] (K=1024), +v+bias+relu  (levels)
template <int MODE>
__global__ __launch_bounds__(256, 3)
void gemm_db(const float* __restrict__ Af32,
             const u16* __restrict__ Abf,
             const u16* __restrict__ embPrev,
             const int2* __restrict__ idx,
             const u16* __restrict__ vLvl,   // [M][512] bf16
             const u16* __restrict__ W,      // bf16, row stride ldb (B^T)
             int ldb,
             const float* __restrict__ bias,
             u16* __restrict__ out,          // [M][512] bf16
             int M, int K, int nBlkM) {
  __shared__ __align__(16) u16 lA[2][128 * BK];   // 2 x 8 KB
  __shared__ __align__(16) u16 lB[2][128 * BK];   // 2 x 8 KB

  const int tid  = threadIdx.x;
  const int lane = tid & 63;
  const int wv   = tid >> 6;
  const int wrow = wv >> 1, wcol = wv & 1;

  // XCD swizzle: 4 n-blocks of one m-block -> same XCD (b%8), adjacent in
  // dispatch order, so A re-reads hit that XCD's L2.
  int mb, nb;
  {
    int b = blockIdx.x;
    if ((nBlkM & 7) == 0) {
      int xcd = b & 7;
      nb = (b >> 3) & 3;
      mb = ((b >> 5) << 3) | xcd;
    } else { nb = b & 3; mb = b >> 2; }
  }
  const int mBase = mb * 128;
  const int n0    = nb * 128;

  const int rowA0 = tid >> 2;       // 0..63 (round 0; +64 for round 1)
  const int q     = tid & 3;
  const int colq  = q * 8;

  const float *af0 = nullptr, *af1 = nullptr;
  const u16 *ab0 = nullptr, *ab1 = nullptr;
  const u16 *aL0 = nullptr, *aR0 = nullptr, *aL1 = nullptr, *aR1 = nullptr;
  {
    int m0 = min(mBase + rowA0, M - 1);
    int m1 = min(mBase + rowA0 + 64, M - 1);
    if (MODE == 0) {
      af0 = Af32 + (size_t)m0 * K;
      af1 = Af32 + (size_t)m1 * K;
    } else if (MODE == 2) {
      ab0 = Abf + (size_t)m0 * K;
      ab1 = Abf + (size_t)m1 * K;
    } else {
      int2 c0 = idx[m0], c1 = idx[m1];
      aL0 = embPrev + (size_t)c0.x * 512;
      aR0 = embPrev + (size_t)c0.y * 512;
      aL1 = embPrev + (size_t)c1.x * 512;
      aR1 = embPrev + (size_t)c1.y * 512;
    }
  }
  const u16* bp0 = W + (size_t)(n0 + rowA0) * ldb + colq;
  const u16* bp1 = W + (size_t)(n0 + rowA0 + 64) * ldb + colq;

  f32x4 acc[4][4] = {};
  const int fm = lane & 15;
  const int kk = (lane >> 4) * 8;
  const int nk = K / BK;

  auto stageB = [&](int buf, int k0) {
    glds16(bp0 + k0, &lB[buf][tid * 8]);
    glds16(bp1 + k0, &lB[buf][(tid + 256) * 8]);
  };
  auto stageA_bf = [&](int buf, int k0) {
    if (MODE == 2) {
      glds16(ab0 + k0 + colq, &lA[buf][tid * 8]);
      glds16(ab1 + k0 + colq, &lA[buf][(tid + 256) * 8]);
    } else {  // MODE 1 gather
      const u16* g0 = ((k0 & 512) ? aR0 : aL0) + (k0 & 511) + colq;
      const u16* g1 = ((k0 & 512) ? aR1 : aL1) + (k0 & 511) + colq;
      glds16(g0, &lA[buf][tid * 8]);
      glds16(g1, &lA[buf][(tid + 256) * 8]);
    }
  };
  auto cvtwrite = [&](int buf, float4 x, float4 y, int slot) {
    union { __hip_bfloat162 h[4]; bf16x8 v; } o;
    o.h[0] = __float22bfloat162_rn({x.x, x.y});
    o.h[1] = __float22bfloat162_rn({x.z, x.w});
    o.h[2] = __float22bfloat162_rn({y.x, y.y});
    o.h[3] = __float22bfloat162_rn({y.z, y.w});
    *(bf16x8*)&lA[buf][slot * 8] = o.v;
  };

  // --- prologue: stage k-step 0 into buffer 0 ---
  if (MODE == 0) {
    const float4* s0 = (const float4*)(af0 + colq);
    const float4* s1 = (const float4*)(af1 + colq);
    cvtwrite(0, s0[0], s0[1], tid);
    cvtwrite(0, s1[0], s1[1], tid + 256);
    stageB(0, 0);
  } else {
    stageA_bf(0, 0);
    stageB(0, 0);
  }

  for (int ks = 0; ks < nk; ks++) {
    const int cur = ks & 1, nxt = cur ^ 1;
    __syncthreads();                 // cur buffer complete (vmcnt+lgkm drained)
    const bool more = (ks + 1 < nk);
    float4 x0, y0, x1, y1;
    if (more) {
      const int k1 = (ks + 1) * BK;
      if (MODE == 0) {               // issue loads now, convert after MFMA
        const float4* s0 = (const float4*)(af0 + k1 + colq);
        const float4* s1 = (const float4*)(af1 + k1 + colq);
        x0 = s0[0]; y0 = s0[1]; x1 = s1[0]; y1 = s1[1];
      } else {
        stageA_bf(nxt, k1);
      }
      stageB(nxt, k1);               // in flight during the MFMA stage below
    }

    bf16x8 av[4], bv[4];
#pragma unroll
    for (int i = 0; i < 4; i++) {
      av[i] = *(const bf16x8*)&lA[cur][(wrow * 64 + i * 16 + fm) * BK + kk];
      bv[i] = *(const bf16x8*)&lB[cur][(wcol * 64 + i * 16 + fm) * BK + kk];
    }
#pragma unroll
    for (int i = 0; i < 4; i++)
#pragma unroll
      for (int j = 0; j < 4; j++)
        acc[i][j] = __builtin_amdgcn_mfma_f32_16x16x32_bf16(av[i], bv[j], acc[i][j], 0, 0, 0);

    if (MODE == 0 && more) {         // convert + LDS-write after MFMA issued
      cvtwrite(nxt, x0, y0, tid);
      cvtwrite(nxt, x1, y1, tid + 256);
    }
  }

  // Epilogue: C/D layout col=lane&15, row=(lane>>4)*4+reg (m89-verified).
  const int r0 = (lane >> 4) * 4;
#pragma unroll
  for (int i = 0; i < 4; i++) {
    int mI = mBase + wrow * 64 + i * 16 + r0;
#pragma unroll
    for (int j = 0; j < 4; j++) {
      int col = n0 + wcol * 64 + j * 16 + fm;
      float bb = (MODE == 2) ? 0.f : bias[col];
#pragma unroll
      for (int r = 0; r < 4; r++) {
        int m = mI + r;
        if (m < M) {
          float v = acc[i][j][r] + bb;
          if (MODE == 1) v += b2f(vLvl[(size_t)m * 512 + col]);
          if (MODE != 2) v = v > 0.f ? v : 0.f;
          out[(size_t)m * 512 + col] = f2b(v);
        }
      }
    }
  }
}

// One launch: convert W_u (512x256) and W_h (512x1536) fp32 -> bf16.
__global__ void cvt_weights(const float* __restrict__ Wu,
                            const float* __restrict__ Wh,
                            u16* __restrict__ Wub, u16* __restrict__ Whb) {
  const int nWu = 512 * 256 / 8;
  const int nWh = 512 * 1536 / 8;
  int i = blockIdx.x * blockDim.x + threadIdx.x;
  const float* src; u16* dst; int c;
  if (i < nWu) { src = Wu; dst = Wub; c = i; }
  else if (i < nWu + nWh) { src = Wh; dst = Whb; c = i - nWu; }
  else return;
  const float4* s = (const float4*)(src + (size_t)c * 8);
  float4 a = s[0], b = s[1];
  union { u16 u[8]; bf16x8 v; } o;
  o.u[0] = f2b(a.x); o.u[1] = f2b(a.y); o.u[2] = f2b(a.z); o.u[3] = f2b(a.w);
  o.u[4] = f2b(b.x); o.u[5] = f2b(b.y); o.u[6] = f2b(b.z); o.u[7] = f2b(b.w);
  *(bf16x8*)(dst + (size_t)c * 8) = o.v;
}

__global__ void cvt_bf16_to_f32(const u16* __restrict__ src, float* __restrict__ dst, int n4) {
  int i = blockIdx.x * blockDim.x + threadIdx.x;
  if (i >= n4) return;
  uint2 p = ((const uint2*)src)[i];
  float4 o;
  o.x = b2f(p.x & 0xffffu); o.y = b2f(p.x >> 16);
  o.z = b2f(p.y & 0xffffu); o.w = b2f(p.y >> 16);
  ((float4*)dst)[i] = o;
}

extern "C" void kernel_launch(void* const* d_in, const int* in_sizes, int n_in,
                              void* d_out, int out_size, void* d_ws, size_t ws_size,
                              hipStream_t stream) {
  const float* contents = (const float*)d_in[0];
  const int2*  children = (const int2*)d_in[1];
  const float* W_u = (const float*)d_in[2];
  const float* b_u = (const float*)d_in[3];
  const float* W_h = (const float*)d_in[4];
  const float* b_h = (const float*)d_in[5];
  float* out = (float*)d_out;

  const int B = 64, D = 11, F = 256, H = 512;
  const int N = B * ((1 << D) - 1);            // 131008
  const int NI = B * ((1 << (D - 1)) - 1);     // 65472

  // Workspace (u16 elems): u_bf [N*512] | v_bf [NI*512] | Wub | Whb.
  // emb ping-pong aliases u's internal rows (dead after the v-GEMM).
  u16* ws16 = (u16*)d_ws;
  u16* u_bf = ws16;
  u16* v_bf = ws16 + (size_t)N * H;
  u16* Wub  = v_bf + (size_t)NI * H;
  u16* Whb  = Wub + 512 * 256;
  u16* embA = u_bf;                            // level-9 dst (32768 rows)
  u16* embB = u_bf + (size_t)32768 * 512;

  // --- weight conversion (single tiny launch) ---
  {
    int n = (512 * 256 + 512 * 1536) / 8;
    cvt_weights<<<(n + 255) / 256, 256, 0, stream>>>(W_u, W_h, Wub, Whb);
  }

  // --- GEMM1: u = relu(contents @ W_u^T + b_u) ---
  {
    int mb = (N + 127) / 128;                  // 1024
    gemm_db<0><<<mb * 4, 256, 0, stream>>>(contents, nullptr, nullptr, nullptr,
                                           nullptr, Wub, F, b_u, u_bf, N, F, mb);
  }

  // --- v-GEMM: v = u[0:NI] @ W_hu^T (W_h cols 1024..1535 in place) ---
  {
    int mb = (NI + 127) / 128;                 // 512
    gemm_db<2><<<mb * 4, 256, 0, stream>>>(nullptr, u_bf, nullptr, nullptr,
                                           nullptr, Whb + 1024, 3 * H, nullptr,
                                           v_bf, NI, H, mb);
  }

  // --- tree levels j = D-2 .. 0 (K=1024 children; v in epilogue) ---
  const u16* embPrev = u_bf + (size_t)NI * H;  // leaves = u[NI:]
  u16* dst = embA;
  for (int j = D - 2; j >= 0; --j) {
    int M = B << j;
    int o = B * ((1 << j) - 1);
    int mb = (M + 127) / 128;
    gemm_db<1><<<mb * 4, 256, 0, stream>>>(nullptr, nullptr, embPrev,
                                           children + o, v_bf + (size_t)o * H,
                                           Whb, 3 * H, b_h, dst, M, 2 * H, mb);
    embPrev = dst;
    dst = (dst == embA) ? embB : embA;
  }

  // --- level-0 emb (64 x 512) -> fp32 output ---
  {
    int n4 = B * H / 4;
    cvt_bf16_to_f32<<<(n4 + 255) / 256, 256, 0, stream>>>(embPrev, out, n4);
  }
}